// Round 1
// baseline (420.629 us; speedup 1.0000x reference)
//
#include <hip/hip_runtime.h>

// StrictLowerTriQSM: f_{i+1} = a_i @ f_i + outer(q_i, x_i), y_i = p_i @ f_i
// N=500000, M=8, K=16. Blocked associative scan, 4 kernels.

#define NTOT 500000
#define CHUNK 245
#define NCHUNK 2048            // 2048*245 = 501760 >= 500000
#define GRPSZ 64
#define NGRP 32                // 2048/64
#define WAVES_PER_BLOCK 4

// workspace float offsets (layouts are column-major: [c][col][row])
#define OFF_AGGA  0u           // NCHUNK*64
#define OFF_AGGB  131072u      // NCHUNK*128
#define OFF_PREFA 393216u      // NCHUNK*64  (group-local exclusive prefix, A)
#define OFF_PREFB 524288u      // NCHUNK*128 (group-local exclusive prefix, B)
#define OFF_GAGA  786432u      // NGRP*64    (group aggregate A)
#define OFF_GAGB  788480u      // NGRP*128   (group aggregate B)
#define OFF_GRPB  792576u      // NGRP*128   (group exclusive prefix, B only)
// total = 796672 floats = 3.19 MB

// ---------------- Phase 1: per-chunk aggregates (A_blk, B_blk) -------------
// One wave per chunk. Lanes 0..15 own B columns, lanes 16..23 own A columns.
// a_i, q_i are wave-uniform -> scalar loads -> SGPR operands.
__global__ __launch_bounds__(256) void k1_aggregate(
    const float* __restrict__ q, const float* __restrict__ a,
    const float* __restrict__ x, float* __restrict__ ws)
{
  const int wid  = __builtin_amdgcn_readfirstlane((int)(threadIdx.x >> 6));
  const int c    = blockIdx.x * WAVES_PER_BLOCK + wid;
  const int lane = (int)(threadIdx.x & 63);
  const bool isB = lane < 16;
  const bool isA = (lane >= 16) && (lane < 24);
  const int bcol = lane & 15;
  const int acol = (lane - 16) & 7;

  float v[8];
#pragma unroll
  for (int m = 0; m < 8; ++m) v[m] = 0.f;
  if (isA) v[acol] = 1.f;           // A starts as identity

  const int start = c * CHUNK;
  int cnt = NTOT - start;
  cnt = cnt < 0 ? 0 : (cnt > CHUNK ? CHUNK : cnt);

  for (int e = 0; e < cnt; ++e) {
    const int i = start + e;
    const float* __restrict__ aw = a + (size_t)i * 64u;   // row-major a[m][t]
    const float* __restrict__ qw = q + (size_t)i * 8u;
    float af[64];
#pragma unroll
    for (int t = 0; t < 64; ++t) af[t] = aw[t];
    float qv[8];
#pragma unroll
    for (int m = 0; m < 8; ++m) qv[m] = qw[m];
    const float xk = x[(size_t)i * 16u + bcol];

    float nv[8];
#pragma unroll
    for (int m = 0; m < 8; ++m) {
      float s = isB ? (qv[m] * xk) : 0.f;
#pragma unroll
      for (int t = 0; t < 8; ++t) s += af[m * 8 + t] * v[t];
      nv[m] = s;
    }
#pragma unroll
    for (int m = 0; m < 8; ++m) v[m] = nv[m];
  }

  if (isB) {
    float* dst = ws + OFF_AGGB + (size_t)c * 128u + (size_t)bcol * 8u;
#pragma unroll
    for (int m = 0; m < 8; ++m) dst[m] = v[m];
  } else if (isA) {
    float* dst = ws + OFF_AGGA + (size_t)c * 64u + (size_t)acol * 8u;
#pragma unroll
    for (int m = 0; m < 8; ++m) dst[m] = v[m];
  }
}

// ---------- Phase 2a: serial scan inside each group of 64 chunks -----------
// Stores group-local EXCLUSIVE prefix pair per chunk + the group aggregate.
__global__ __launch_bounds__(64) void k2a_groupscan(float* __restrict__ ws)
{
  const int g    = blockIdx.x;
  const int lane = (int)(threadIdx.x & 63);
  const bool isB = lane < 16;
  const bool isA = (lane >= 16) && (lane < 24);
  const int bcol = lane & 15;
  const int acol = (lane - 16) & 7;

  float v[8];
#pragma unroll
  for (int m = 0; m < 8; ++m) v[m] = 0.f;
  if (isA) v[acol] = 1.f;           // run = identity

  for (int j = 0; j < GRPSZ; ++j) {
    const int c = g * GRPSZ + j;
    if (isB) {
      float* dst = ws + OFF_PREFB + (size_t)c * 128u + (size_t)bcol * 8u;
#pragma unroll
      for (int m = 0; m < 8; ++m) dst[m] = v[m];
    } else if (isA) {
      float* dst = ws + OFF_PREFA + (size_t)c * 64u + (size_t)acol * 8u;
#pragma unroll
      for (int m = 0; m < 8; ++m) dst[m] = v[m];
    }
    // run = agg_c ∘ run : (Ac@Arun, Ac@Brun + Bc)
    const float* __restrict__ aA = ws + OFF_AGGA + (size_t)c * 64u;
    float af[64];                    // af[t*8+m] = Ac[m][t] (col-major)
#pragma unroll
    for (int t = 0; t < 64; ++t) af[t] = aA[t];
    float nv[8];
#pragma unroll
    for (int m = 0; m < 8; ++m) {
      float s = 0.f;
#pragma unroll
      for (int t = 0; t < 8; ++t) s += af[t * 8 + m] * v[t];
      nv[m] = s;
    }
    if (isB) {
      const float* __restrict__ bB =
          ws + OFF_AGGB + (size_t)c * 128u + (size_t)bcol * 8u;
#pragma unroll
      for (int m = 0; m < 8; ++m) nv[m] += bB[m];
    }
#pragma unroll
    for (int m = 0; m < 8; ++m) v[m] = nv[m];
  }

  if (isB) {
    float* dst = ws + OFF_GAGB + (size_t)g * 128u + (size_t)bcol * 8u;
#pragma unroll
    for (int m = 0; m < 8; ++m) dst[m] = v[m];
  } else if (isA) {
    float* dst = ws + OFF_GAGA + (size_t)g * 64u + (size_t)acol * 8u;
#pragma unroll
    for (int m = 0; m < 8; ++m) dst[m] = v[m];
  }
}

// ---------- Phase 2b: single-wave scan over the 32 group aggregates --------
// Stores group-exclusive prefix B only (that's all phase 3 needs).
__global__ __launch_bounds__(64) void k2b_topscan(float* __restrict__ ws)
{
  const int lane = (int)(threadIdx.x & 63);
  const bool isB = lane < 16;
  const bool isA = (lane >= 16) && (lane < 24);
  const int bcol = lane & 15;
  const int acol = (lane - 16) & 7;

  float v[8];
#pragma unroll
  for (int m = 0; m < 8; ++m) v[m] = 0.f;
  if (isA) v[acol] = 1.f;

  for (int g = 0; g < NGRP; ++g) {
    if (isB) {
      float* dst = ws + OFF_GRPB + (size_t)g * 128u + (size_t)bcol * 8u;
#pragma unroll
      for (int m = 0; m < 8; ++m) dst[m] = v[m];
    }
    const float* __restrict__ aA = ws + OFF_GAGA + (size_t)g * 64u;
    float af[64];
#pragma unroll
    for (int t = 0; t < 64; ++t) af[t] = aA[t];
    float nv[8];
#pragma unroll
    for (int m = 0; m < 8; ++m) {
      float s = 0.f;
#pragma unroll
      for (int t = 0; t < 8; ++t) s += af[t * 8 + m] * v[t];
      nv[m] = s;
    }
    if (isB) {
      const float* __restrict__ bB =
          ws + OFF_GAGB + (size_t)g * 128u + (size_t)bcol * 8u;
#pragma unroll
      for (int m = 0; m < 8; ++m) nv[m] += bB[m];
    }
#pragma unroll
    for (int m = 0; m < 8; ++m) v[m] = nv[m];
  }
}

// ---------- Phase 3: replay each chunk from its carry, emit y --------------
// f0(chunk) = prefA_c @ grpPrefB_g + prefB_c ; then the plain recurrence.
// y_i = p_i @ f_i uses the PRE-update carry (scan emits carry before update).
__global__ __launch_bounds__(256) void k3_output(
    const float* __restrict__ p, const float* __restrict__ q,
    const float* __restrict__ a, const float* __restrict__ x,
    const float* __restrict__ ws, float* __restrict__ out)
{
  const int wid  = __builtin_amdgcn_readfirstlane((int)(threadIdx.x >> 6));
  const int c    = blockIdx.x * WAVES_PER_BLOCK + wid;
  const int lane = (int)(threadIdx.x & 63);
  const int k    = lane & 15;          // all 64 lanes mirror k<16 work
  const bool active = lane < 16;
  const int g    = c >> 6;             // GRPSZ = 64

  // init f column k
  const float* __restrict__ pA = ws + OFF_PREFA + (size_t)c * 64u;
  float af[64];
#pragma unroll
  for (int t = 0; t < 64; ++t) af[t] = pA[t];     // af[t*8+m] = prefA[m][t]
  const float* __restrict__ gBp = ws + OFF_GRPB + (size_t)g * 128u + (size_t)k * 8u;
  const float* __restrict__ lBp = ws + OFF_PREFB + (size_t)c * 128u + (size_t)k * 8u;
  float gcol[8];
#pragma unroll
  for (int t = 0; t < 8; ++t) gcol[t] = gBp[t];
  float f[8];
#pragma unroll
  for (int m = 0; m < 8; ++m) {
    float s = lBp[m];
#pragma unroll
    for (int t = 0; t < 8; ++t) s += af[t * 8 + m] * gcol[t];
    f[m] = s;
  }

  const int start = c * CHUNK;
  int cnt = NTOT - start;
  cnt = cnt < 0 ? 0 : (cnt > CHUNK ? CHUNK : cnt);

  for (int e = 0; e < cnt; ++e) {
    const int i = start + e;
    const float* __restrict__ aw = a + (size_t)i * 64u;
    const float* __restrict__ qw = q + (size_t)i * 8u;
    const float* __restrict__ pw = p + (size_t)i * 8u;
    float am[64];
#pragma unroll
    for (int t = 0; t < 64; ++t) am[t] = aw[t];   // row-major a[m][t]
    float qv[8], pv[8];
#pragma unroll
    for (int m = 0; m < 8; ++m) { qv[m] = qw[m]; pv[m] = pw[m]; }
    const float xk = x[(size_t)i * 16u + k];

    float y = 0.f;
#pragma unroll
    for (int m = 0; m < 8; ++m) y += pv[m] * f[m];
    if (active) out[(size_t)i * 16u + k] = y;

    float nf[8];
#pragma unroll
    for (int m = 0; m < 8; ++m) {
      float s = qv[m] * xk;
#pragma unroll
      for (int t = 0; t < 8; ++t) s += am[m * 8 + t] * f[t];
      nf[m] = s;
    }
#pragma unroll
    for (int m = 0; m < 8; ++m) f[m] = nf[m];
  }
}

extern "C" void kernel_launch(void* const* d_in, const int* in_sizes, int n_in,
                              void* d_out, int out_size, void* d_ws, size_t ws_size,
                              hipStream_t stream)
{
  const float* p = (const float*)d_in[0];
  const float* q = (const float*)d_in[1];
  const float* a = (const float*)d_in[2];
  const float* x = (const float*)d_in[3];
  float* out = (float*)d_out;
  float* ws  = (float*)d_ws;

  dim3 blk(256);
  dim3 grid1(NCHUNK / WAVES_PER_BLOCK);   // 512 blocks, 4 waves each
  hipLaunchKernelGGL(k1_aggregate, grid1, blk, 0, stream, q, a, x, ws);
  hipLaunchKernelGGL(k2a_groupscan, dim3(NGRP), dim3(64), 0, stream, ws);
  hipLaunchKernelGGL(k2b_topscan, dim3(1), dim3(64), 0, stream, ws);
  hipLaunchKernelGGL(k3_output, grid1, blk, 0, stream, p, q, a, x, ws, out);
}

// Round 2
// 366.919 us; speedup vs baseline: 1.1464x; 1.1464x over previous
//
#include <hip/hip_runtime.h>

// StrictLowerTriQSM: f_{i+1} = a_i @ f_i + outer(q_i, x_i), y_i = p_i @ f_i
// N=500000, M=8, K=16. Blocked associative scan, 4 kernels.
// Round 1: NCHUNK 2048->8192 for full occupancy (8 waves/SIMD); in-place
// aggregate->prefix conversion keeps ws at 6.4 MB.

#define NTOT 500000
#define CHUNK 62
#define NCHUNK 8192            // 8192*62 = 507904 >= 500000
#define GRPSZ 64
#define NGRP 128               // 8192/64
#define WAVES_PER_BLOCK 4

// workspace float offsets (column-major: [c][col][row])
// After k1: AGGA/AGGB hold per-chunk aggregates.
// After k2a: same arrays hold group-LOCAL EXCLUSIVE prefixes; GAGA/GAGB hold
//            group aggregates.
// After k2b: GAGB holds group-exclusive B prefixes (GAGA unchanged).
#define OFF_AGGA  0u           // NCHUNK*64  = 524288
#define OFF_AGGB  524288u      // NCHUNK*128 = 1048576
#define OFF_GAGA  1572864u     // NGRP*64    = 8192
#define OFF_GAGB  1581056u     // NGRP*128   = 16384
// total = 1597440 floats = 6.39 MB

// ---------------- Phase 1: per-chunk aggregates (A_blk, B_blk) -------------
// One wave per chunk. Lanes 0..15 own B columns, lanes 16..23 own A columns.
// a_i, q_i are wave-uniform -> scalar loads -> SGPR operands.
__global__ __launch_bounds__(256) void k1_aggregate(
    const float* __restrict__ q, const float* __restrict__ a,
    const float* __restrict__ x, float* __restrict__ ws)
{
  const int wid  = __builtin_amdgcn_readfirstlane((int)(threadIdx.x >> 6));
  const int c    = blockIdx.x * WAVES_PER_BLOCK + wid;
  const int lane = (int)(threadIdx.x & 63);
  const bool isB = lane < 16;
  const bool isA = (lane >= 16) && (lane < 24);
  const int bcol = lane & 15;
  const int acol = (lane - 16) & 7;

  float v[8];
#pragma unroll
  for (int m = 0; m < 8; ++m) v[m] = 0.f;
  if (isA) v[acol] = 1.f;           // A starts as identity

  const int start = c * CHUNK;
  int cnt = NTOT - start;
  cnt = cnt < 0 ? 0 : (cnt > CHUNK ? CHUNK : cnt);

  for (int e = 0; e < cnt; ++e) {
    const int i = start + e;
    const float* __restrict__ aw = a + (size_t)i * 64u;   // row-major a[m][t]
    const float* __restrict__ qw = q + (size_t)i * 8u;
    float af[64];
#pragma unroll
    for (int t = 0; t < 64; ++t) af[t] = aw[t];
    float qv[8];
#pragma unroll
    for (int m = 0; m < 8; ++m) qv[m] = qw[m];
    const float xk = x[(size_t)i * 16u + bcol];

    float nv[8];
#pragma unroll
    for (int m = 0; m < 8; ++m) {
      float s = isB ? (qv[m] * xk) : 0.f;
#pragma unroll
      for (int t = 0; t < 8; ++t) s += af[m * 8 + t] * v[t];
      nv[m] = s;
    }
#pragma unroll
    for (int m = 0; m < 8; ++m) v[m] = nv[m];
  }

  if (isB) {
    float* dst = ws + OFF_AGGB + (size_t)c * 128u + (size_t)bcol * 8u;
#pragma unroll
    for (int m = 0; m < 8; ++m) dst[m] = v[m];
  } else if (isA) {
    float* dst = ws + OFF_AGGA + (size_t)c * 64u + (size_t)acol * 8u;
#pragma unroll
    for (int m = 0; m < 8; ++m) dst[m] = v[m];
  }
}

// ---------- Phase 2a: serial scan inside each group of 64 chunks -----------
// IN-PLACE: reads the chunk aggregate, overwrites the slot with the
// group-local EXCLUSIVE prefix, accumulates the group aggregate.
__global__ __launch_bounds__(64) void k2a_groupscan(float* __restrict__ ws)
{
  const int g    = blockIdx.x;
  const int lane = (int)(threadIdx.x & 63);
  const bool isB = lane < 16;
  const bool isA = (lane >= 16) && (lane < 24);
  const int bcol = lane & 15;
  const int acol = (lane - 16) & 7;

  float v[8];
#pragma unroll
  for (int m = 0; m < 8; ++m) v[m] = 0.f;
  if (isA) v[acol] = 1.f;           // run = identity

  for (int j = 0; j < GRPSZ; ++j) {
    const int c = g * GRPSZ + j;
    // load aggregate of chunk c
    const float* __restrict__ aA = ws + OFF_AGGA + (size_t)c * 64u;
    float af[64];                    // af[t*8+m] = Ac[m][t] (col-major)
#pragma unroll
    for (int t = 0; t < 64; ++t) af[t] = aA[t];
    float bB[8];
    if (isB) {
      const float* __restrict__ src =
          ws + OFF_AGGB + (size_t)c * 128u + (size_t)bcol * 8u;
#pragma unroll
      for (int m = 0; m < 8; ++m) bB[m] = src[m];
    }
    // overwrite slot with the exclusive prefix (= current run)
    if (isB) {
      float* dst = ws + OFF_AGGB + (size_t)c * 128u + (size_t)bcol * 8u;
#pragma unroll
      for (int m = 0; m < 8; ++m) dst[m] = v[m];
    } else if (isA) {
      float* dst = ws + OFF_AGGA + (size_t)c * 64u + (size_t)acol * 8u;
#pragma unroll
      for (int m = 0; m < 8; ++m) dst[m] = v[m];
    }
    // run = agg_c ∘ run : (Ac@Arun, Ac@Brun + Bc)
    float nv[8];
#pragma unroll
    for (int m = 0; m < 8; ++m) {
      float s = 0.f;
#pragma unroll
      for (int t = 0; t < 8; ++t) s += af[t * 8 + m] * v[t];
      nv[m] = s;
    }
    if (isB) {
#pragma unroll
      for (int m = 0; m < 8; ++m) nv[m] += bB[m];
    }
#pragma unroll
    for (int m = 0; m < 8; ++m) v[m] = nv[m];
  }

  if (isB) {
    float* dst = ws + OFF_GAGB + (size_t)g * 128u + (size_t)bcol * 8u;
#pragma unroll
    for (int m = 0; m < 8; ++m) dst[m] = v[m];
  } else if (isA) {
    float* dst = ws + OFF_GAGA + (size_t)g * 64u + (size_t)acol * 8u;
#pragma unroll
    for (int m = 0; m < 8; ++m) dst[m] = v[m];
  }
}

// ---------- Phase 2b: single-wave scan over the NGRP group aggregates ------
// IN-PLACE on GAGB: overwrites each group's B aggregate with the
// group-EXCLUSIVE B prefix (all phase 3 needs). GAGA is read-only.
__global__ __launch_bounds__(64) void k2b_topscan(float* __restrict__ ws)
{
  const int lane = (int)(threadIdx.x & 63);
  const bool isB = lane < 16;
  const bool isA = (lane >= 16) && (lane < 24);
  const int bcol = lane & 15;
  const int acol = (lane - 16) & 7;

  float v[8];
#pragma unroll
  for (int m = 0; m < 8; ++m) v[m] = 0.f;
  if (isA) v[acol] = 1.f;

  for (int g = 0; g < NGRP; ++g) {
    const float* __restrict__ aA = ws + OFF_GAGA + (size_t)g * 64u;
    float af[64];
#pragma unroll
    for (int t = 0; t < 64; ++t) af[t] = aA[t];
    float bB[8];
    if (isB) {
      const float* __restrict__ src =
          ws + OFF_GAGB + (size_t)g * 128u + (size_t)bcol * 8u;
#pragma unroll
      for (int m = 0; m < 8; ++m) bB[m] = src[m];
      float* dst = ws + OFF_GAGB + (size_t)g * 128u + (size_t)bcol * 8u;
#pragma unroll
      for (int m = 0; m < 8; ++m) dst[m] = v[m];
    }
    float nv[8];
#pragma unroll
    for (int m = 0; m < 8; ++m) {
      float s = 0.f;
#pragma unroll
      for (int t = 0; t < 8; ++t) s += af[t * 8 + m] * v[t];
      nv[m] = s;
    }
    if (isB) {
#pragma unroll
      for (int m = 0; m < 8; ++m) nv[m] += bB[m];
    }
#pragma unroll
    for (int m = 0; m < 8; ++m) v[m] = nv[m];
  }
}

// ---------- Phase 3: replay each chunk from its carry, emit y --------------
// f0(chunk) = prefA_c @ grpPrefB_g + prefB_c ; then the plain recurrence.
// y_i = p_i @ f_i uses the PRE-update carry (scan emits carry before update).
__global__ __launch_bounds__(256) void k3_output(
    const float* __restrict__ p, const float* __restrict__ q,
    const float* __restrict__ a, const float* __restrict__ x,
    const float* __restrict__ ws, float* __restrict__ out)
{
  const int wid  = __builtin_amdgcn_readfirstlane((int)(threadIdx.x >> 6));
  const int c    = blockIdx.x * WAVES_PER_BLOCK + wid;
  const int lane = (int)(threadIdx.x & 63);
  const int k    = lane & 15;          // all 64 lanes mirror k<16 work
  const bool active = lane < 16;
  const int g    = c >> 6;             // GRPSZ = 64

  // init f column k = prefA_c @ grpB_g[:,k] + prefB_c[:,k]
  const float* __restrict__ pA = ws + OFF_AGGA + (size_t)c * 64u;
  float af[64];
#pragma unroll
  for (int t = 0; t < 64; ++t) af[t] = pA[t];     // af[t*8+m] = prefA[m][t]
  const float* __restrict__ gBp = ws + OFF_GAGB + (size_t)g * 128u + (size_t)k * 8u;
  const float* __restrict__ lBp = ws + OFF_AGGB + (size_t)c * 128u + (size_t)k * 8u;
  float gcol[8];
#pragma unroll
  for (int t = 0; t < 8; ++t) gcol[t] = gBp[t];
  float f[8];
#pragma unroll
  for (int m = 0; m < 8; ++m) {
    float s = lBp[m];
#pragma unroll
    for (int t = 0; t < 8; ++t) s += af[t * 8 + m] * gcol[t];
    f[m] = s;
  }

  const int start = c * CHUNK;
  int cnt = NTOT - start;
  cnt = cnt < 0 ? 0 : (cnt > CHUNK ? CHUNK : cnt);

  for (int e = 0; e < cnt; ++e) {
    const int i = start + e;
    const float* __restrict__ aw = a + (size_t)i * 64u;
    const float* __restrict__ qw = q + (size_t)i * 8u;
    const float* __restrict__ pw = p + (size_t)i * 8u;
    float am[64];
#pragma unroll
    for (int t = 0; t < 64; ++t) am[t] = aw[t];   // row-major a[m][t]
    float qv[8], pv[8];
#pragma unroll
    for (int m = 0; m < 8; ++m) { qv[m] = qw[m]; pv[m] = pw[m]; }
    const float xk = x[(size_t)i * 16u + k];

    float y = 0.f;
#pragma unroll
    for (int m = 0; m < 8; ++m) y += pv[m] * f[m];
    if (active) out[(size_t)i * 16u + k] = y;

    float nf[8];
#pragma unroll
    for (int m = 0; m < 8; ++m) {
      float s = qv[m] * xk;
#pragma unroll
      for (int t = 0; t < 8; ++t) s += am[m * 8 + t] * f[t];
      nf[m] = s;
    }
#pragma unroll
    for (int m = 0; m < 8; ++m) f[m] = nf[m];
  }
}

extern "C" void kernel_launch(void* const* d_in, const int* in_sizes, int n_in,
                              void* d_out, int out_size, void* d_ws, size_t ws_size,
                              hipStream_t stream)
{
  const float* p = (const float*)d_in[0];
  const float* q = (const float*)d_in[1];
  const float* a = (const float*)d_in[2];
  const float* x = (const float*)d_in[3];
  float* out = (float*)d_out;
  float* ws  = (float*)d_ws;

  dim3 blk(256);
  dim3 grid1(NCHUNK / WAVES_PER_BLOCK);   // 2048 blocks, 4 waves each
  hipLaunchKernelGGL(k1_aggregate, grid1, blk, 0, stream, q, a, x, ws);
  hipLaunchKernelGGL(k2a_groupscan, dim3(NGRP), dim3(64), 0, stream, ws);
  hipLaunchKernelGGL(k2b_topscan, dim3(1), dim3(64), 0, stream, ws);
  hipLaunchKernelGGL(k3_output, grid1, blk, 0, stream, p, q, a, x, ws, out);
}